// Round 12
// baseline (229.502 us; speedup 1.0000x reference)
//
#include <hip/hip_runtime.h>
#include <hip/hip_fp16.h>
#include <cstdint>
#include <cstddef>

// ---------------------------------------------------------------------------
// 2-layer GCN: h1 = x@W1; s = softmax(A_norm@h1 + b1); out = A_norm@(s@W2) + b2
// CSR build: wg-private two-level counting sort (zero global atomics).
// GEMMs: fp16 MFMA (v_mfma_f32_16x16x32_f16), zero LDS, pre-packed W.
// Aggregation: static 16/8-lane groups, TWO consecutive nodes per group with
// interleaved edge streams (8 gathers in flight/group, pairwise degree
// averaging). No perm / no work-stealing (both measured regressions).
// ---------------------------------------------------------------------------

#define BSHIFT 8              // 256 nodes per bucket
#define NBPAD 512             // padded bucket count (NB=391 for N=100K)
#define NWG 256               // edge slices / scatter workgroups
#define CAP 6144              // LDS reorder buffer (mean bucket ~4096 edges)

typedef _Float16 half8 __attribute__((ext_vector_type(8)));
typedef float f32x4 __attribute__((ext_vector_type(4)));

__device__ __forceinline__ void h8_to_f(const uint4& u, float* f) {
  const __half2* hp = (const __half2*)&u;
#pragma unroll
  for (int i = 0; i < 4; ++i) {
    float2 t = __half22float2(hp[i]);
    f[2 * i] = t.x;
    f[2 * i + 1] = t.y;
  }
}

__device__ __forceinline__ void fma8(float* acc, float w, const float* v) {
#pragma unroll
  for (int i = 0; i < 8; ++i) acc[i] = fmaf(w, v[i], acc[i]);
}

// inclusive scan of v across a 256-thread block; wsums is __shared__ int[4]
__device__ __forceinline__ int block_scan256(int v, int* wsums) {
  const int lane = threadIdx.x & 63;
  const int wid = threadIdx.x >> 6;
  int x = v;
#pragma unroll
  for (int d = 1; d < 64; d <<= 1) {
    int y = __shfl_up(x, d);
    if (lane >= d) x += y;
  }
  if (lane == 63) wsums[wid] = x;
  __syncthreads();
  int off = 0;
#pragma unroll
  for (int j = 0; j < 4; ++j)
    if (j < wid) off += wsums[j];
  return off + x;
}

// Pass 1: per-wg LDS histogram of its edge slice -> counts[wg*NBPAD + b]
__global__ __launch_bounds__(256) void wg_count(const int* __restrict__ dst,
                                                int* __restrict__ counts,
                                                int E, int nb, int slice) {
  __shared__ int lh[NBPAD];
  const int w = blockIdx.x;
  for (int i = threadIdx.x; i < nb; i += 256) lh[i] = 0;
  __syncthreads();
  const int e0 = w * slice;
  const int e1 = min(e0 + slice, E);
  for (int e = e0 + threadIdx.x; e < e1; e += 256)
    atomicAdd(&lh[dst[e] >> BSHIFT], 1);
  __syncthreads();
  for (int i = threadIdx.x; i < nb; i += 256) counts[(size_t)w * NBPAD + i] = lh[i];
}

// Pass 2: single block — per-bucket totals + exclusive scan -> bstart[0..nb]
__global__ __launch_bounds__(1024) void scan_buckets(const int* __restrict__ counts,
                                                     int* __restrict__ bstart,
                                                     int* __restrict__ row_start,
                                                     int nb, int n, int E) {
  __shared__ int wsum[16];
  const int tid = threadIdx.x;
  const int lane = tid & 63;
  const int wid = tid >> 6;
  int v = 0;
  if (tid < nb) {
#pragma unroll 4
    for (int i = 0; i < NWG; ++i) v += counts[(size_t)i * NBPAD + tid];
  }
  int x = v;
#pragma unroll
  for (int d = 1; d < 64; d <<= 1) {
    int y = __shfl_up(x, d);
    if (lane >= d) x += y;
  }
  if (lane == 63) wsum[wid] = x;
  __syncthreads();
  if (wid == 0) {
    int w = (lane < 16) ? wsum[lane] : 0;
#pragma unroll
    for (int d = 1; d < 16; d <<= 1) {
      int y = __shfl_up(w, d);
      if (lane >= d) w += y;
    }
    if (lane < 16) wsum[lane] = w;
  }
  __syncthreads();
  int boff = (wid > 0) ? wsum[wid - 1] : 0;
  int incl = boff + x;
  if (tid < nb) {
    bstart[tid] = incl - v;
    if (tid == nb - 1) bstart[nb] = incl;
  }
  if (tid == 0) row_start[n] = E;
}

// Pass 3: one block per bucket — exclusive scan across wgs -> cur[wg][b]
__global__ __launch_bounds__(256) void cell_scan(const int* __restrict__ counts,
                                                 const int* __restrict__ bstart,
                                                 int* __restrict__ cur, int nb) {
  __shared__ int wsums[4];
  const int b = blockIdx.x;
  const int tid = threadIdx.x;
  int v = counts[(size_t)tid * NBPAD + b];
  int incl = block_scan256(v, wsums);
  cur[(size_t)tid * NBPAD + b] = bstart[b] + incl - v;
}

// Pass 4: scatter with LDS cursors — each (wg,bucket) range written by one wg
__global__ __launch_bounds__(256) void wg_scatter(const int* __restrict__ src,
                                                  const int* __restrict__ dst,
                                                  const int* __restrict__ cur,
                                                  unsigned* __restrict__ staging,
                                                  int E, int nb, int slice) {
  __shared__ int lc[NBPAD];
  const int w = blockIdx.x;
  for (int i = threadIdx.x; i < nb; i += 256) lc[i] = cur[(size_t)w * NBPAD + i];
  __syncthreads();
  const int e0 = w * slice;
  const int e1 = min(e0 + slice, E);
  for (int e = e0 + threadIdx.x; e < e1; e += 256) {
    int d = dst[e];
    int p = atomicAdd(&lc[d >> BSHIFT], 1);
    staging[p] = ((unsigned)(d & 255) << 24) | (unsigned)src[e];
  }
}

// Pass 5: per-bucket finalize — row_start, dinv, coalesced csr_src
__global__ __launch_bounds__(256) void bucket_finalize(const unsigned* __restrict__ staging,
                                                       const int* __restrict__ bstart,
                                                       int* __restrict__ csr_src,
                                                       int* __restrict__ row_start,
                                                       float* __restrict__ dinv, int n) {
  __shared__ int lcnt[256];
  __shared__ int lcur[256];
  __shared__ int wsums[4];
  __shared__ int lbuf[CAP];
  const int b = blockIdx.x;
  const int tid = threadIdx.x;
  const int n0 = b << BSHIFT;
  const int s0 = bstart[b];
  const int cnt = bstart[b + 1] - s0;

  lcnt[tid] = 0;
  __syncthreads();
  for (int i = tid; i < cnt; i += 256)
    atomicAdd(&lcnt[staging[s0 + i] >> 24], 1);
  __syncthreads();

  const int v = lcnt[tid];
  const int incl = block_scan256(v, wsums);
  const int excl = incl - v;
  lcur[tid] = excl;
  const int node = n0 + tid;
  if (node < n) {
    row_start[node] = s0 + excl;
    dinv[node] = rsqrtf((float)v + 1.0f);
  }
  __syncthreads();

  for (int i = tid; i < cnt; i += 256) {
    unsigned p = staging[s0 + i];
    int pos = atomicAdd(&lcur[p >> 24], 1);
    int s = (int)(p & 0xFFFFFFu);
    if (pos < CAP) lbuf[pos] = s;
    else csr_src[s0 + pos] = s;  // overflow fallback (statistically never)
  }
  __syncthreads();
  const int lim = cnt < CAP ? cnt : CAP;
  for (int i = tid; i < lim; i += 256) csr_src[s0 + i] = lbuf[i];
}

__global__ __launch_bounds__(256) void make_pack(const int* __restrict__ csr_src,
                                                 const float* __restrict__ dinv,
                                                 int2* __restrict__ pack, int E) {
  int e = blockIdx.x * 256 + threadIdx.x;
  if (e < E) {
    int s = csr_src[e];
    pack[e] = make_int2(s, __float_as_int(dinv[s]));
  }
}

// Pack W[128][M] fp32 -> Wp fp16 fragment order:
// Wp[((t*M + c)*4 + g)*8 + j] = W[t*32 + g*8 + j][c]
template <int M>
__global__ __launch_bounds__(256) void pack_w(const float* __restrict__ W,
                                              _Float16* __restrict__ Wp) {
  int e = blockIdx.x * 256 + threadIdx.x;
  if (e < 128 * M) {
    int k = e / M, c = e % M;
    int t = k >> 5, g = (k >> 3) & 3, j = k & 7;
    Wp[(((size_t)t * M + c) * 4 + g) * 8 + j] = (_Float16)W[e];
  }
}

// H[N,M] = X[N,128] @ W[128,M] via v_mfma_f32_16x16x32_f16. Zero LDS.
template <int M, bool HIN>
__global__ __launch_bounds__(256) void gemm_mfma(const void* __restrict__ Xp,
                                                 const _Float16* __restrict__ Wp,
                                                 _Float16* __restrict__ H, int N) {
  constexpr int CT = M / 16;
  const int wave = threadIdx.x >> 6;
  const int lane = threadIdx.x & 63;
  const int row0 = (blockIdx.x * 4 + wave) * 16;
  if (row0 >= N) return;
  const int r = lane & 15;
  const int g = lane >> 4;
  int row = row0 + r;
  if (row >= N) row = N - 1;

  f32x4 acc[CT];
#pragma unroll
  for (int c = 0; c < CT; ++c) acc[c] = (f32x4){0.f, 0.f, 0.f, 0.f};

#pragma unroll
  for (int t = 0; t < 4; ++t) {
    half8 a;
    if constexpr (HIN) {
      a = *(const half8*)((const _Float16*)Xp + (size_t)row * 128 + t * 32 + g * 8);
    } else {
      const float* xp = (const float*)Xp + (size_t)row * 128 + t * 32 + g * 8;
      float4 x0 = *(const float4*)xp;
      float4 x1 = *(const float4*)(xp + 4);
      a[0] = (_Float16)x0.x; a[1] = (_Float16)x0.y;
      a[2] = (_Float16)x0.z; a[3] = (_Float16)x0.w;
      a[4] = (_Float16)x1.x; a[5] = (_Float16)x1.y;
      a[6] = (_Float16)x1.z; a[7] = (_Float16)x1.w;
    }
#pragma unroll
    for (int c = 0; c < CT; ++c) {
      half8 b = *(const half8*)(Wp + (((size_t)t * M + c * 16 + r) * 4 + g) * 8);
      acc[c] = __builtin_amdgcn_mfma_f32_16x16x32_f16(a, b, acc[c], 0, 0, 0);
    }
  }

#pragma unroll
  for (int c = 0; c < CT; ++c) {
#pragma unroll
    for (int i = 0; i < 4; ++i) {
      int rr = row0 + 4 * g + i;
      if (rr < N) H[(size_t)rr * M + c * 16 + r] = (_Float16)acc[c][i];
    }
  }
}

// --- aggregate helpers ---
template <int LPG>
__device__ __forceinline__ void edge4(const uint4* __restrict__ hv,
                                      const int2* __restrict__ pack,
                                      int e, int lane, float* acc) {
  int2 p[4];
  uint4 r[4];
#pragma unroll
  for (int j = 0; j < 4; ++j) p[j] = pack[e + j];
#pragma unroll
  for (int j = 0; j < 4; ++j) r[j] = hv[(size_t)p[j].x * LPG + lane];
#pragma unroll
  for (int j = 0; j < 4; ++j) {
    float v[8];
    h8_to_f(r[j], v);
    fma8(acc, __int_as_float(p[j].y), v);
  }
}

template <int LPG>
__device__ __forceinline__ void edge1(const uint4* __restrict__ hv,
                                      const int2* __restrict__ pack,
                                      int e, int lane, float* acc) {
  int2 p = pack[e];
  uint4 r = hv[(size_t)p.x * LPG + lane];
  float v[8];
  h8_to_f(r, v);
  fma8(acc, __int_as_float(p.y), v);
}

// bias + optional softmax + store for one node's 8 per-lane features
template <int F, bool SM, bool OUTHALF>
__device__ __forceinline__ void agg_finish(int node, float* acc, float di,
                                           const float* __restrict__ bias,
                                           void* __restrict__ out, int lane) {
  constexpr int LPG = F / 8;
  const float4* bv = (const float4*)bias;
  float4 b0 = bv[lane * 2], b1 = bv[lane * 2 + 1];
  acc[0] = fmaf(di, acc[0], b0.x);
  acc[1] = fmaf(di, acc[1], b0.y);
  acc[2] = fmaf(di, acc[2], b0.z);
  acc[3] = fmaf(di, acc[3], b0.w);
  acc[4] = fmaf(di, acc[4], b1.x);
  acc[5] = fmaf(di, acc[5], b1.y);
  acc[6] = fmaf(di, acc[6], b1.z);
  acc[7] = fmaf(di, acc[7], b1.w);

  if constexpr (SM) {
    float m = acc[0];
#pragma unroll
    for (int i = 1; i < 8; ++i) m = fmaxf(m, acc[i]);
#pragma unroll
    for (int off = LPG / 2; off >= 1; off >>= 1) m = fmaxf(m, __shfl_xor(m, off));
    float ex[8], ssum = 0.f;
#pragma unroll
    for (int i = 0; i < 8; ++i) {
      ex[i] = __expf(acc[i] - m);
      ssum += ex[i];
    }
#pragma unroll
    for (int off = LPG / 2; off >= 1; off >>= 1) ssum += __shfl_xor(ssum, off);
    float r = 1.0f / ssum;
#pragma unroll
    for (int i = 0; i < 8; ++i) acc[i] = ex[i] * r;
  }

  if constexpr (OUTHALF) {
    union { __half2 h2[4]; uint4 u; } cv;
#pragma unroll
    for (int i = 0; i < 4; ++i)
      cv.h2[i] = __floats2half2_rn(acc[2 * i], acc[2 * i + 1]);
    ((uint4*)out)[(size_t)node * LPG + lane] = cv.u;
  } else {
    float4* ov = (float4*)out;
    ov[(size_t)node * (F / 4) + lane * 2] =
        make_float4(acc[0], acc[1], acc[2], acc[3]);
    ov[(size_t)node * (F / 4) + lane * 2 + 1] =
        make_float4(acc[4], acc[5], acc[6], acc[7]);
  }
}

// out[node] = di*( sum_e w_e*h[src_e] + di*h[node] ) + bias (+softmax).
// Each LPG-lane group owns TWO consecutive nodes; the main loop interleaves
// both edge streams (8 independent gathers in flight per group) and the
// pairing averages degree variance. Edge order per node unchanged.
template <int F, bool SM, bool OUTHALF>
__global__ __launch_bounds__(256) void aggregate(const __half* __restrict__ h,
                                                 const int* __restrict__ row_start,
                                                 const int2* __restrict__ pack,
                                                 const float* __restrict__ dinv,
                                                 const float* __restrict__ bias,
                                                 void* __restrict__ out, int n) {
  constexpr int LPG = F / 8;      // lanes per group: 16 (F=128) / 8 (F=64)
  constexpr int GPB = 256 / LPG;  // groups per block: 16 / 32
  const int gid = blockIdx.x * GPB + (int)(threadIdx.x / LPG);
  const int lane = threadIdx.x % LPG;
  const int na = 2 * gid;
  if (na >= n) return;
  const int nb = na + 1;
  const bool hasb = nb < n;

  const uint4* hv = (const uint4*)h;
  const float dia = dinv[na];
  const float dib = hasb ? dinv[nb] : 0.f;

  float acca[8], accb[8];
  {
    uint4 su = hv[(size_t)na * LPG + lane];
    float sf[8];
    h8_to_f(su, sf);
#pragma unroll
    for (int i = 0; i < 8; ++i) acca[i] = dia * sf[i];
  }
  if (hasb) {
    uint4 su = hv[(size_t)nb * LPG + lane];
    float sf[8];
    h8_to_f(su, sf);
#pragma unroll
    for (int i = 0; i < 8; ++i) accb[i] = dib * sf[i];
  } else {
#pragma unroll
    for (int i = 0; i < 8; ++i) accb[i] = 0.f;
  }

  int ea = row_start[na];
  const int ea1 = row_start[na + 1];
  int eb = ea1;  // rows contiguous: row_start[nb] == row_start[na+1]
  const int eb1 = hasb ? row_start[nb + 1] : ea1;

  // interleaved main loop: 4 gathers per stream, 8 in flight
  while (ea + 4 <= ea1 && eb + 4 <= eb1) {
    int2 pa[4], pb[4];
    uint4 ra[4], rb[4];
#pragma unroll
    for (int j = 0; j < 4; ++j) pa[j] = pack[ea + j];
#pragma unroll
    for (int j = 0; j < 4; ++j) pb[j] = pack[eb + j];
#pragma unroll
    for (int j = 0; j < 4; ++j) ra[j] = hv[(size_t)pa[j].x * LPG + lane];
#pragma unroll
    for (int j = 0; j < 4; ++j) rb[j] = hv[(size_t)pb[j].x * LPG + lane];
#pragma unroll
    for (int j = 0; j < 4; ++j) {
      float v[8];
      h8_to_f(ra[j], v);
      fma8(acca, __int_as_float(pa[j].y), v);
    }
#pragma unroll
    for (int j = 0; j < 4; ++j) {
      float v[8];
      h8_to_f(rb[j], v);
      fma8(accb, __int_as_float(pb[j].y), v);
    }
    ea += 4;
    eb += 4;
  }
  // drains (deterministic, per-node edge order preserved)
  for (; ea + 4 <= ea1; ea += 4) edge4<LPG>(hv, pack, ea, lane, acca);
  for (; ea < ea1; ++ea) edge1<LPG>(hv, pack, ea, lane, acca);
  for (; eb + 4 <= eb1; eb += 4) edge4<LPG>(hv, pack, eb, lane, accb);
  for (; eb < eb1; ++eb) edge1<LPG>(hv, pack, eb, lane, accb);

  agg_finish<F, SM, OUTHALF>(na, acca, dia, bias, out, lane);
  if (hasb) agg_finish<F, SM, OUTHALF>(nb, accb, dib, bias, out, lane);
}

extern "C" void kernel_launch(void* const* d_in, const int* in_sizes, int n_in,
                              void* d_out, int out_size, void* d_ws, size_t ws_size,
                              hipStream_t stream) {
  const float* x  = (const float*)d_in[0];
  const float* W1 = (const float*)d_in[1];
  const float* b1 = (const float*)d_in[2];
  const float* W2 = (const float*)d_in[3];
  const float* b2 = (const float*)d_in[4];
  const int*   ei = (const int*)d_in[5];

  const int N = in_sizes[0] / 128;
  const int E = in_sizes[5] / 2;
  const int NB = (N + 255) >> BSHIFT;          // 391 for N=100K (<= NBPAD)
  const int SLICE = (E + NWG - 1) / NWG;
  const int* srcp = ei;
  const int* dstp = ei + E;

  auto align256 = [](size_t v) { return (v + 255) & ~(size_t)255; };
  char* ws = (char*)d_ws;
  size_t o_dinv   = 0;
  size_t o_rs     = align256(o_dinv + (size_t)N * 4);
  size_t o_cnts   = align256(o_rs + (size_t)(N + 1) * 4);
  size_t o_cur    = align256(o_cnts + (size_t)NWG * NBPAD * 4);
  size_t o_bstart = align256(o_cur + (size_t)NWG * NBPAD * 4);
  size_t o_wp1    = align256(o_bstart + (size_t)(NBPAD + 1) * 4);
  size_t o_wp2    = align256(o_wp1 + (size_t)128 * 128 * 2);
  size_t o_stg    = align256(o_wp2 + (size_t)128 * 64 * 2);
  size_t o_csr    = align256(o_stg + (size_t)E * 4);
  size_t o_pack   = align256(o_csr + (size_t)E * 4);
  size_t o_h1     = align256(o_pack + (size_t)E * 8);
  size_t o_s      = align256(o_h1 + (size_t)N * 128 * 2);

  float*    dinv     = (float*)(ws + o_dinv);
  int*      rowstart = (int*)(ws + o_rs);
  int*      counts   = (int*)(ws + o_cnts);
  int*      cur      = (int*)(ws + o_cur);
  int*      bstart   = (int*)(ws + o_bstart);
  _Float16* wp1      = (_Float16*)(ws + o_wp1);
  _Float16* wp2      = (_Float16*)(ws + o_wp2);
  unsigned* staging  = (unsigned*)(ws + o_stg);
  int*      csr_src  = (int*)(ws + o_csr);
  int2*     pack     = (int2*)(ws + o_pack);
  _Float16* h1       = (_Float16*)(ws + o_h1);  // [N,128] fp16; reused as h2 [N,64]
  _Float16* sbuf     = (_Float16*)(ws + o_s);   // [N,128] fp16 softmax output

  // CSR build — no global atomics anywhere
  wg_count<<<NWG, 256, 0, stream>>>(dstp, counts, E, NB, SLICE);
  scan_buckets<<<1, 1024, 0, stream>>>(counts, bstart, rowstart, NB, N, E);
  cell_scan<<<NB, 256, 0, stream>>>(counts, bstart, cur, NB);
  wg_scatter<<<NWG, 256, 0, stream>>>(srcp, dstp, cur, staging, E, NB, SLICE);
  bucket_finalize<<<NB, 256, 0, stream>>>(staging, bstart, csr_src, rowstart, dinv, N);
  make_pack<<<(E + 255) / 256, 256, 0, stream>>>(csr_src, dinv, pack, E);

  // Weight packing (tiny)
  pack_w<128><<<(128 * 128 + 255) / 256, 256, 0, stream>>>(W1, wp1);
  pack_w<64><<<(128 * 64 + 255) / 256, 256, 0, stream>>>(W2, wp2);

  // Layer 1
  gemm_mfma<128, false><<<(N + 63) / 64, 256, 0, stream>>>(x, wp1, h1, N);
  aggregate<128, true, true><<<(N + 31) / 32, 256, 0, stream>>>(
      (const __half*)h1, rowstart, pack, dinv, b1, sbuf, N);
  // Layer 2
  gemm_mfma<64, true><<<(N + 63) / 64, 256, 0, stream>>>(sbuf, wp2, h1, N);
  aggregate<64, false, false><<<(N + 63) / 64, 256, 0, stream>>>(
      (const __half*)h1, rowstart, pack, dinv, b2, d_out, N);
}

// Round 13
// 206.499 us; speedup vs baseline: 1.1114x; 1.1114x over previous
//
#include <hip/hip_runtime.h>
#include <hip/hip_fp16.h>
#include <cstdint>
#include <cstddef>

// ---------------------------------------------------------------------------
// 2-layer GCN: h1 = x@W1; s = softmax(A_norm@h1 + b1); out = A_norm@(s@W2) + b2
// CSR build: wg-private two-level counting sort (zero global atomics).
// GEMMs: fp16 MFMA (v_mfma_f32_16x16x32_f16), zero LDS, pre-packed W.
// Aggregation: R5 static 16/8-lane groups, one node per group, with the
// pack[] stream SOFTWARE-PIPELINED one batch ahead so pack loads overlap the
// row gathers (breaks the 2-deep dependent load chain).
// ---------------------------------------------------------------------------

#define BSHIFT 8              // 256 nodes per bucket
#define NBPAD 512             // padded bucket count (NB=391 for N=100K)
#define NWG 256               // edge slices / scatter workgroups
#define CAP 6144              // LDS reorder buffer (mean bucket ~4096 edges)

typedef _Float16 half8 __attribute__((ext_vector_type(8)));
typedef float f32x4 __attribute__((ext_vector_type(4)));

__device__ __forceinline__ void h8_to_f(const uint4& u, float* f) {
  const __half2* hp = (const __half2*)&u;
#pragma unroll
  for (int i = 0; i < 4; ++i) {
    float2 t = __half22float2(hp[i]);
    f[2 * i] = t.x;
    f[2 * i + 1] = t.y;
  }
}

__device__ __forceinline__ void fma8(float* acc, float w, const float* v) {
#pragma unroll
  for (int i = 0; i < 8; ++i) acc[i] = fmaf(w, v[i], acc[i]);
}

// inclusive scan of v across a 256-thread block; wsums is __shared__ int[4]
__device__ __forceinline__ int block_scan256(int v, int* wsums) {
  const int lane = threadIdx.x & 63;
  const int wid = threadIdx.x >> 6;
  int x = v;
#pragma unroll
  for (int d = 1; d < 64; d <<= 1) {
    int y = __shfl_up(x, d);
    if (lane >= d) x += y;
  }
  if (lane == 63) wsums[wid] = x;
  __syncthreads();
  int off = 0;
#pragma unroll
  for (int j = 0; j < 4; ++j)
    if (j < wid) off += wsums[j];
  return off + x;
}

// Pass 1: per-wg LDS histogram of its edge slice -> counts[wg*NBPAD + b]
__global__ __launch_bounds__(256) void wg_count(const int* __restrict__ dst,
                                                int* __restrict__ counts,
                                                int E, int nb, int slice) {
  __shared__ int lh[NBPAD];
  const int w = blockIdx.x;
  for (int i = threadIdx.x; i < nb; i += 256) lh[i] = 0;
  __syncthreads();
  const int e0 = w * slice;
  const int e1 = min(e0 + slice, E);
  for (int e = e0 + threadIdx.x; e < e1; e += 256)
    atomicAdd(&lh[dst[e] >> BSHIFT], 1);
  __syncthreads();
  for (int i = threadIdx.x; i < nb; i += 256) counts[(size_t)w * NBPAD + i] = lh[i];
}

// Pass 2: single block — per-bucket totals + exclusive scan -> bstart[0..nb]
__global__ __launch_bounds__(1024) void scan_buckets(const int* __restrict__ counts,
                                                     int* __restrict__ bstart,
                                                     int* __restrict__ row_start,
                                                     int nb, int n, int E) {
  __shared__ int wsum[16];
  const int tid = threadIdx.x;
  const int lane = tid & 63;
  const int wid = tid >> 6;
  int v = 0;
  if (tid < nb) {
#pragma unroll 4
    for (int i = 0; i < NWG; ++i) v += counts[(size_t)i * NBPAD + tid];
  }
  int x = v;
#pragma unroll
  for (int d = 1; d < 64; d <<= 1) {
    int y = __shfl_up(x, d);
    if (lane >= d) x += y;
  }
  if (lane == 63) wsum[wid] = x;
  __syncthreads();
  if (wid == 0) {
    int w = (lane < 16) ? wsum[lane] : 0;
#pragma unroll
    for (int d = 1; d < 16; d <<= 1) {
      int y = __shfl_up(w, d);
      if (lane >= d) w += y;
    }
    if (lane < 16) wsum[lane] = w;
  }
  __syncthreads();
  int boff = (wid > 0) ? wsum[wid - 1] : 0;
  int incl = boff + x;
  if (tid < nb) {
    bstart[tid] = incl - v;
    if (tid == nb - 1) bstart[nb] = incl;
  }
  if (tid == 0) row_start[n] = E;
}

// Pass 3: one block per bucket — exclusive scan across wgs -> cur[wg][b]
__global__ __launch_bounds__(256) void cell_scan(const int* __restrict__ counts,
                                                 const int* __restrict__ bstart,
                                                 int* __restrict__ cur, int nb) {
  __shared__ int wsums[4];
  const int b = blockIdx.x;
  const int tid = threadIdx.x;
  int v = counts[(size_t)tid * NBPAD + b];
  int incl = block_scan256(v, wsums);
  cur[(size_t)tid * NBPAD + b] = bstart[b] + incl - v;
}

// Pass 4: scatter with LDS cursors — each (wg,bucket) range written by one wg
__global__ __launch_bounds__(256) void wg_scatter(const int* __restrict__ src,
                                                  const int* __restrict__ dst,
                                                  const int* __restrict__ cur,
                                                  unsigned* __restrict__ staging,
                                                  int E, int nb, int slice) {
  __shared__ int lc[NBPAD];
  const int w = blockIdx.x;
  for (int i = threadIdx.x; i < nb; i += 256) lc[i] = cur[(size_t)w * NBPAD + i];
  __syncthreads();
  const int e0 = w * slice;
  const int e1 = min(e0 + slice, E);
  for (int e = e0 + threadIdx.x; e < e1; e += 256) {
    int d = dst[e];
    int p = atomicAdd(&lc[d >> BSHIFT], 1);
    staging[p] = ((unsigned)(d & 255) << 24) | (unsigned)src[e];
  }
}

// Pass 5: per-bucket finalize — row_start, dinv, coalesced csr_src
__global__ __launch_bounds__(256) void bucket_finalize(const unsigned* __restrict__ staging,
                                                       const int* __restrict__ bstart,
                                                       int* __restrict__ csr_src,
                                                       int* __restrict__ row_start,
                                                       float* __restrict__ dinv, int n) {
  __shared__ int lcnt[256];
  __shared__ int lcur[256];
  __shared__ int wsums[4];
  __shared__ int lbuf[CAP];
  const int b = blockIdx.x;
  const int tid = threadIdx.x;
  const int n0 = b << BSHIFT;
  const int s0 = bstart[b];
  const int cnt = bstart[b + 1] - s0;

  lcnt[tid] = 0;
  __syncthreads();
  for (int i = tid; i < cnt; i += 256)
    atomicAdd(&lcnt[staging[s0 + i] >> 24], 1);
  __syncthreads();

  const int v = lcnt[tid];
  const int incl = block_scan256(v, wsums);
  const int excl = incl - v;
  lcur[tid] = excl;
  const int node = n0 + tid;
  if (node < n) {
    row_start[node] = s0 + excl;
    dinv[node] = rsqrtf((float)v + 1.0f);
  }
  __syncthreads();

  for (int i = tid; i < cnt; i += 256) {
    unsigned p = staging[s0 + i];
    int pos = atomicAdd(&lcur[p >> 24], 1);
    int s = (int)(p & 0xFFFFFFu);
    if (pos < CAP) lbuf[pos] = s;
    else csr_src[s0 + pos] = s;  // overflow fallback (statistically never)
  }
  __syncthreads();
  const int lim = cnt < CAP ? cnt : CAP;
  for (int i = tid; i < lim; i += 256) csr_src[s0 + i] = lbuf[i];
}

__global__ __launch_bounds__(256) void make_pack(const int* __restrict__ csr_src,
                                                 const float* __restrict__ dinv,
                                                 int2* __restrict__ pack, int E) {
  int e = blockIdx.x * 256 + threadIdx.x;
  if (e < E) {
    int s = csr_src[e];
    pack[e] = make_int2(s, __float_as_int(dinv[s]));
  }
}

// Pack W[128][M] fp32 -> Wp fp16 fragment order:
// Wp[((t*M + c)*4 + g)*8 + j] = W[t*32 + g*8 + j][c]
template <int M>
__global__ __launch_bounds__(256) void pack_w(const float* __restrict__ W,
                                              _Float16* __restrict__ Wp) {
  int e = blockIdx.x * 256 + threadIdx.x;
  if (e < 128 * M) {
    int k = e / M, c = e % M;
    int t = k >> 5, g = (k >> 3) & 3, j = k & 7;
    Wp[(((size_t)t * M + c) * 4 + g) * 8 + j] = (_Float16)W[e];
  }
}

// H[N,M] = X[N,128] @ W[128,M] via v_mfma_f32_16x16x32_f16. Zero LDS.
template <int M, bool HIN>
__global__ __launch_bounds__(256) void gemm_mfma(const void* __restrict__ Xp,
                                                 const _Float16* __restrict__ Wp,
                                                 _Float16* __restrict__ H, int N) {
  constexpr int CT = M / 16;
  const int wave = threadIdx.x >> 6;
  const int lane = threadIdx.x & 63;
  const int row0 = (blockIdx.x * 4 + wave) * 16;
  if (row0 >= N) return;
  const int r = lane & 15;
  const int g = lane >> 4;
  int row = row0 + r;
  if (row >= N) row = N - 1;

  f32x4 acc[CT];
#pragma unroll
  for (int c = 0; c < CT; ++c) acc[c] = (f32x4){0.f, 0.f, 0.f, 0.f};

#pragma unroll
  for (int t = 0; t < 4; ++t) {
    half8 a;
    if constexpr (HIN) {
      a = *(const half8*)((const _Float16*)Xp + (size_t)row * 128 + t * 32 + g * 8);
    } else {
      const float* xp = (const float*)Xp + (size_t)row * 128 + t * 32 + g * 8;
      float4 x0 = *(const float4*)xp;
      float4 x1 = *(const float4*)(xp + 4);
      a[0] = (_Float16)x0.x; a[1] = (_Float16)x0.y;
      a[2] = (_Float16)x0.z; a[3] = (_Float16)x0.w;
      a[4] = (_Float16)x1.x; a[5] = (_Float16)x1.y;
      a[6] = (_Float16)x1.z; a[7] = (_Float16)x1.w;
    }
#pragma unroll
    for (int c = 0; c < CT; ++c) {
      half8 b = *(const half8*)(Wp + (((size_t)t * M + c * 16 + r) * 4 + g) * 8);
      acc[c] = __builtin_amdgcn_mfma_f32_16x16x32_f16(a, b, acc[c], 0, 0, 0);
    }
  }

#pragma unroll
  for (int c = 0; c < CT; ++c) {
#pragma unroll
    for (int i = 0; i < 4; ++i) {
      int rr = row0 + 4 * g + i;
      if (rr < N) H[(size_t)rr * M + c * 16 + r] = (_Float16)acc[c][i];
    }
  }
}

// --- aggregate helpers ---
template <int LPG>
__device__ __forceinline__ void edge1(const uint4* __restrict__ hv,
                                      const int2* __restrict__ pack,
                                      int e, int lane, float* acc) {
  int2 p = pack[e];
  uint4 r = hv[(size_t)p.x * LPG + lane];
  float v[8];
  h8_to_f(r, v);
  fma8(acc, __int_as_float(p.y), v);
}

// out[node] = di*( sum_e w_e*h[src_e] + di*h[node] ) + bias (+softmax).
// Static groups of F/8 lanes, ONE node per group (the proven R5 shape).
// The pack[] stream is pipelined one 4-edge batch ahead: the next batch's
// pack loads are issued alongside the current batch's row gathers.
template <int F, bool SM, bool OUTHALF>
__global__ __launch_bounds__(256) void aggregate(const __half* __restrict__ h,
                                                 const int* __restrict__ row_start,
                                                 const int2* __restrict__ pack,
                                                 const float* __restrict__ dinv,
                                                 const float* __restrict__ bias,
                                                 void* __restrict__ out, int n) {
  constexpr int LPG = F / 8;      // lanes per group: 16 (F=128) / 8 (F=64)
  constexpr int GPB = 256 / LPG;  // groups per block: 16 / 32
  const int node = blockIdx.x * GPB + (int)(threadIdx.x / LPG);
  const int lane = threadIdx.x % LPG;
  if (node >= n) return;

  const uint4* hv = (const uint4*)h;
  const float di = dinv[node];

  float acc[8];
  {
    uint4 su = hv[(size_t)node * LPG + lane];
    float sf[8];
    h8_to_f(su, sf);
#pragma unroll
    for (int i = 0; i < 8; ++i) acc[i] = di * sf[i];
  }

  int e = row_start[node];
  const int e1 = row_start[node + 1];

  int2 p[4];
  if (e + 4 <= e1) {
#pragma unroll
    for (int j = 0; j < 4; ++j) p[j] = pack[e + j];
  }
  // steady state: gather rows for batch p, prefetch next batch's pack
  while (e + 8 <= e1) {
    uint4 r[4];
#pragma unroll
    for (int j = 0; j < 4; ++j) r[j] = hv[(size_t)p[j].x * LPG + lane];
    int2 pn[4];
#pragma unroll
    for (int j = 0; j < 4; ++j) pn[j] = pack[e + 4 + j];
#pragma unroll
    for (int j = 0; j < 4; ++j) {
      float v[8];
      h8_to_f(r[j], v);
      fma8(acc, __int_as_float(p[j].y), v);
    }
#pragma unroll
    for (int j = 0; j < 4; ++j) p[j] = pn[j];
    e += 4;
  }
  // last full batch (pack already in registers)
  if (e + 4 <= e1) {
    uint4 r[4];
#pragma unroll
    for (int j = 0; j < 4; ++j) r[j] = hv[(size_t)p[j].x * LPG + lane];
#pragma unroll
    for (int j = 0; j < 4; ++j) {
      float v[8];
      h8_to_f(r[j], v);
      fma8(acc, __int_as_float(p[j].y), v);
    }
    e += 4;
  }
  for (; e < e1; ++e) edge1<LPG>(hv, pack, e, lane, acc);

  {
    const float4* bv = (const float4*)bias;
    float4 b0 = bv[lane * 2], b1 = bv[lane * 2 + 1];
    acc[0] = fmaf(di, acc[0], b0.x);
    acc[1] = fmaf(di, acc[1], b0.y);
    acc[2] = fmaf(di, acc[2], b0.z);
    acc[3] = fmaf(di, acc[3], b0.w);
    acc[4] = fmaf(di, acc[4], b1.x);
    acc[5] = fmaf(di, acc[5], b1.y);
    acc[6] = fmaf(di, acc[6], b1.z);
    acc[7] = fmaf(di, acc[7], b1.w);
  }

  if constexpr (SM) {
    float m = acc[0];
#pragma unroll
    for (int i = 1; i < 8; ++i) m = fmaxf(m, acc[i]);
#pragma unroll
    for (int off = LPG / 2; off >= 1; off >>= 1) m = fmaxf(m, __shfl_xor(m, off));
    float ex[8], ssum = 0.f;
#pragma unroll
    for (int i = 0; i < 8; ++i) {
      ex[i] = __expf(acc[i] - m);
      ssum += ex[i];
    }
#pragma unroll
    for (int off = LPG / 2; off >= 1; off >>= 1) ssum += __shfl_xor(ssum, off);
    float r = 1.0f / ssum;
#pragma unroll
    for (int i = 0; i < 8; ++i) acc[i] = ex[i] * r;
  }

  if constexpr (OUTHALF) {
    union { __half2 h2[4]; uint4 u; } cv;
#pragma unroll
    for (int i = 0; i < 4; ++i)
      cv.h2[i] = __floats2half2_rn(acc[2 * i], acc[2 * i + 1]);
    ((uint4*)out)[(size_t)node * LPG + lane] = cv.u;
  } else {
    float4* ov = (float4*)out;
    ov[(size_t)node * (F / 4) + lane * 2] =
        make_float4(acc[0], acc[1], acc[2], acc[3]);
    ov[(size_t)node * (F / 4) + lane * 2 + 1] =
        make_float4(acc[4], acc[5], acc[6], acc[7]);
  }
}

extern "C" void kernel_launch(void* const* d_in, const int* in_sizes, int n_in,
                              void* d_out, int out_size, void* d_ws, size_t ws_size,
                              hipStream_t stream) {
  const float* x  = (const float*)d_in[0];
  const float* W1 = (const float*)d_in[1];
  const float* b1 = (const float*)d_in[2];
  const float* W2 = (const float*)d_in[3];
  const float* b2 = (const float*)d_in[4];
  const int*   ei = (const int*)d_in[5];

  const int N = in_sizes[0] / 128;
  const int E = in_sizes[5] / 2;
  const int NB = (N + 255) >> BSHIFT;          // 391 for N=100K (<= NBPAD)
  const int SLICE = (E + NWG - 1) / NWG;
  const int* srcp = ei;
  const int* dstp = ei + E;

  auto align256 = [](size_t v) { return (v + 255) & ~(size_t)255; };
  char* ws = (char*)d_ws;
  size_t o_dinv   = 0;
  size_t o_rs     = align256(o_dinv + (size_t)N * 4);
  size_t o_cnts   = align256(o_rs + (size_t)(N + 1) * 4);
  size_t o_cur    = align256(o_cnts + (size_t)NWG * NBPAD * 4);
  size_t o_bstart = align256(o_cur + (size_t)NWG * NBPAD * 4);
  size_t o_wp1    = align256(o_bstart + (size_t)(NBPAD + 1) * 4);
  size_t o_wp2    = align256(o_wp1 + (size_t)128 * 128 * 2);
  size_t o_stg    = align256(o_wp2 + (size_t)128 * 64 * 2);
  size_t o_csr    = align256(o_stg + (size_t)E * 4);
  size_t o_pack   = align256(o_csr + (size_t)E * 4);
  size_t o_h1     = align256(o_pack + (size_t)E * 8);
  size_t o_s      = align256(o_h1 + (size_t)N * 128 * 2);

  float*    dinv     = (float*)(ws + o_dinv);
  int*      rowstart = (int*)(ws + o_rs);
  int*      counts   = (int*)(ws + o_cnts);
  int*      cur      = (int*)(ws + o_cur);
  int*      bstart   = (int*)(ws + o_bstart);
  _Float16* wp1      = (_Float16*)(ws + o_wp1);
  _Float16* wp2      = (_Float16*)(ws + o_wp2);
  unsigned* staging  = (unsigned*)(ws + o_stg);
  int*      csr_src  = (int*)(ws + o_csr);
  int2*     pack     = (int2*)(ws + o_pack);
  _Float16* h1       = (_Float16*)(ws + o_h1);  // [N,128] fp16; reused as h2 [N,64]
  _Float16* sbuf     = (_Float16*)(ws + o_s);   // [N,128] fp16 softmax output

  // CSR build — no global atomics anywhere
  wg_count<<<NWG, 256, 0, stream>>>(dstp, counts, E, NB, SLICE);
  scan_buckets<<<1, 1024, 0, stream>>>(counts, bstart, rowstart, NB, N, E);
  cell_scan<<<NB, 256, 0, stream>>>(counts, bstart, cur, NB);
  wg_scatter<<<NWG, 256, 0, stream>>>(srcp, dstp, cur, staging, E, NB, SLICE);
  bucket_finalize<<<NB, 256, 0, stream>>>(staging, bstart, csr_src, rowstart, dinv, N);
  make_pack<<<(E + 255) / 256, 256, 0, stream>>>(csr_src, dinv, pack, E);

  // Weight packing (tiny)
  pack_w<128><<<(128 * 128 + 255) / 256, 256, 0, stream>>>(W1, wp1);
  pack_w<64><<<(128 * 64 + 255) / 256, 256, 0, stream>>>(W2, wp2);

  // Layer 1
  gemm_mfma<128, false><<<(N + 63) / 64, 256, 0, stream>>>(x, wp1, h1, N);
  aggregate<128, true, true><<<(N + 15) / 16, 256, 0, stream>>>(
      (const __half*)h1, rowstart, pack, dinv, b1, sbuf, N);
  // Layer 2
  gemm_mfma<64, true><<<(N + 63) / 64, 256, 0, stream>>>(sbuf, wp2, h1, N);
  aggregate<64, false, false><<<(N + 31) / 32, 256, 0, stream>>>(
      (const __half*)h1, rowstart, pack, dinv, b2, d_out, N);
}

// Round 14
// 202.689 us; speedup vs baseline: 1.1323x; 1.0188x over previous
//
#include <hip/hip_runtime.h>
#include <hip/hip_fp16.h>
#include <cstdint>
#include <cstddef>

// ---------------------------------------------------------------------------
// 2-layer GCN: h1 = x@W1; s = softmax(A_norm@h1 + b1); out = A_norm@(s@W2) + b2
// CSR build: wg-private two-level counting sort (zero global atomics);
// finalize split into hist (row_start/dinv) + pack (reorder -> (src,w) pairs,
// no csr_src intermediate).
// GEMMs: fp16 MFMA (v_mfma_f32_16x16x32_f16), zero LDS, pre-packed W.
// Aggregation: 16/8-lane groups, pack stream software-pipelined one batch
// ahead; rows processed as ceil(deg/4) MASKED 4-wide batches (no serial tail).
// ---------------------------------------------------------------------------

#define BSHIFT 8              // 256 nodes per bucket
#define NBPAD 512             // padded bucket count (NB=391 for N=100K)
#define NWG 256               // edge slices / scatter workgroups
#define CAP 6144              // LDS reorder buffer (mean bucket ~4096 edges)

typedef _Float16 half8 __attribute__((ext_vector_type(8)));
typedef float f32x4 __attribute__((ext_vector_type(4)));

__device__ __forceinline__ void h8_to_f(const uint4& u, float* f) {
  const __half2* hp = (const __half2*)&u;
#pragma unroll
  for (int i = 0; i < 4; ++i) {
    float2 t = __half22float2(hp[i]);
    f[2 * i] = t.x;
    f[2 * i + 1] = t.y;
  }
}

__device__ __forceinline__ void fma8(float* acc, float w, const float* v) {
#pragma unroll
  for (int i = 0; i < 8; ++i) acc[i] = fmaf(w, v[i], acc[i]);
}

// inclusive scan of v across a 256-thread block; wsums is __shared__ int[4]
__device__ __forceinline__ int block_scan256(int v, int* wsums) {
  const int lane = threadIdx.x & 63;
  const int wid = threadIdx.x >> 6;
  int x = v;
#pragma unroll
  for (int d = 1; d < 64; d <<= 1) {
    int y = __shfl_up(x, d);
    if (lane >= d) x += y;
  }
  if (lane == 63) wsums[wid] = x;
  __syncthreads();
  int off = 0;
#pragma unroll
  for (int j = 0; j < 4; ++j)
    if (j < wid) off += wsums[j];
  return off + x;
}

// Pass 1: per-wg LDS histogram of its edge slice -> counts[wg*NBPAD + b]
__global__ __launch_bounds__(256) void wg_count(const int* __restrict__ dst,
                                                int* __restrict__ counts,
                                                int E, int nb, int slice) {
  __shared__ int lh[NBPAD];
  const int w = blockIdx.x;
  for (int i = threadIdx.x; i < nb; i += 256) lh[i] = 0;
  __syncthreads();
  const int e0 = w * slice;
  const int e1 = min(e0 + slice, E);
  for (int e = e0 + threadIdx.x; e < e1; e += 256)
    atomicAdd(&lh[dst[e] >> BSHIFT], 1);
  __syncthreads();
  for (int i = threadIdx.x; i < nb; i += 256) counts[(size_t)w * NBPAD + i] = lh[i];
}

// Pass 2: single block — per-bucket totals + exclusive scan -> bstart[0..nb]
__global__ __launch_bounds__(1024) void scan_buckets(const int* __restrict__ counts,
                                                     int* __restrict__ bstart,
                                                     int* __restrict__ row_start,
                                                     int nb, int n, int E) {
  __shared__ int wsum[16];
  const int tid = threadIdx.x;
  const int lane = tid & 63;
  const int wid = tid >> 6;
  int v = 0;
  if (tid < nb) {
#pragma unroll 4
    for (int i = 0; i < NWG; ++i) v += counts[(size_t)i * NBPAD + tid];
  }
  int x = v;
#pragma unroll
  for (int d = 1; d < 64; d <<= 1) {
    int y = __shfl_up(x, d);
    if (lane >= d) x += y;
  }
  if (lane == 63) wsum[wid] = x;
  __syncthreads();
  if (wid == 0) {
    int w = (lane < 16) ? wsum[lane] : 0;
#pragma unroll
    for (int d = 1; d < 16; d <<= 1) {
      int y = __shfl_up(w, d);
      if (lane >= d) w += y;
    }
    if (lane < 16) wsum[lane] = w;
  }
  __syncthreads();
  int boff = (wid > 0) ? wsum[wid - 1] : 0;
  int incl = boff + x;
  if (tid < nb) {
    bstart[tid] = incl - v;
    if (tid == nb - 1) bstart[nb] = incl;
  }
  if (tid == 0) row_start[n] = E;
}

// Pass 3: one block per bucket — exclusive scan across wgs -> cur[wg][b]
__global__ __launch_bounds__(256) void cell_scan(const int* __restrict__ counts,
                                                 const int* __restrict__ bstart,
                                                 int* __restrict__ cur, int nb) {
  __shared__ int wsums[4];
  const int b = blockIdx.x;
  const int tid = threadIdx.x;
  int v = counts[(size_t)tid * NBPAD + b];
  int incl = block_scan256(v, wsums);
  cur[(size_t)tid * NBPAD + b] = bstart[b] + incl - v;
}

// Pass 4: scatter with LDS cursors — each (wg,bucket) range written by one wg
__global__ __launch_bounds__(256) void wg_scatter(const int* __restrict__ src,
                                                  const int* __restrict__ dst,
                                                  const int* __restrict__ cur,
                                                  unsigned* __restrict__ staging,
                                                  int E, int nb, int slice) {
  __shared__ int lc[NBPAD];
  const int w = blockIdx.x;
  for (int i = threadIdx.x; i < nb; i += 256) lc[i] = cur[(size_t)w * NBPAD + i];
  __syncthreads();
  const int e0 = w * slice;
  const int e1 = min(e0 + slice, E);
  for (int e = e0 + threadIdx.x; e < e1; e += 256) {
    int d = dst[e];
    int p = atomicAdd(&lc[d >> BSHIFT], 1);
    staging[p] = ((unsigned)(d & 255) << 24) | (unsigned)src[e];
  }
}

// Pass 5a: per-bucket histogram -> row_start, dinv
__global__ __launch_bounds__(256) void bucket_hist(const unsigned* __restrict__ staging,
                                                   const int* __restrict__ bstart,
                                                   int* __restrict__ row_start,
                                                   float* __restrict__ dinv, int n) {
  __shared__ int lcnt[256];
  __shared__ int wsums[4];
  const int b = blockIdx.x;
  const int tid = threadIdx.x;
  const int n0 = b << BSHIFT;
  const int s0 = bstart[b];
  const int cnt = bstart[b + 1] - s0;

  lcnt[tid] = 0;
  __syncthreads();
  for (int i = tid; i < cnt; i += 256)
    atomicAdd(&lcnt[staging[s0 + i] >> 24], 1);
  __syncthreads();

  const int v = lcnt[tid];
  const int incl = block_scan256(v, wsums);
  const int node = n0 + tid;
  if (node < n) {
    row_start[node] = s0 + incl - v;
    dinv[node] = rsqrtf((float)v + 1.0f);
  }
}

// Pass 5b: per-bucket reorder -> pack[(src, dinv[src])] directly (no csr_src)
__global__ __launch_bounds__(256) void bucket_pack(const unsigned* __restrict__ staging,
                                                   const int* __restrict__ bstart,
                                                   const int* __restrict__ row_start,
                                                   const float* __restrict__ dinv,
                                                   int2* __restrict__ pack, int n) {
  __shared__ int lcur[256];
  __shared__ int lbuf[CAP];
  const int b = blockIdx.x;
  const int tid = threadIdx.x;
  const int n0 = b << BSHIFT;
  const int s0 = bstart[b];
  const int cnt = bstart[b + 1] - s0;

  const int node = n0 + tid;
  lcur[tid] = (node < n) ? (row_start[node] - s0) : 0;
  __syncthreads();

  for (int i = tid; i < cnt; i += 256) {
    unsigned p = staging[s0 + i];
    int pos = atomicAdd(&lcur[p >> 24], 1);
    int s = (int)(p & 0xFFFFFFu);
    if (pos < CAP) lbuf[pos] = s;
    else pack[s0 + pos] = make_int2(s, __float_as_int(dinv[s]));  // overflow
  }
  __syncthreads();
  const int lim = cnt < CAP ? cnt : CAP;
  for (int i = tid; i < lim; i += 256) {
    int s = lbuf[i];
    pack[s0 + i] = make_int2(s, __float_as_int(dinv[s]));
  }
}

// Pack W[128][M] fp32 -> Wp fp16 fragment order:
// Wp[((t*M + c)*4 + g)*8 + j] = W[t*32 + g*8 + j][c]
template <int M>
__global__ __launch_bounds__(256) void pack_w(const float* __restrict__ W,
                                              _Float16* __restrict__ Wp) {
  int e = blockIdx.x * 256 + threadIdx.x;
  if (e < 128 * M) {
    int k = e / M, c = e % M;
    int t = k >> 5, g = (k >> 3) & 3, j = k & 7;
    Wp[(((size_t)t * M + c) * 4 + g) * 8 + j] = (_Float16)W[e];
  }
}

// H[N,M] = X[N,128] @ W[128,M] via v_mfma_f32_16x16x32_f16. Zero LDS.
template <int M, bool HIN>
__global__ __launch_bounds__(256) void gemm_mfma(const void* __restrict__ Xp,
                                                 const _Float16* __restrict__ Wp,
                                                 _Float16* __restrict__ H, int N) {
  constexpr int CT = M / 16;
  const int wave = threadIdx.x >> 6;
  const int lane = threadIdx.x & 63;
  const int row0 = (blockIdx.x * 4 + wave) * 16;
  if (row0 >= N) return;
  const int r = lane & 15;
  const int g = lane >> 4;
  int row = row0 + r;
  if (row >= N) row = N - 1;

  f32x4 acc[CT];
#pragma unroll
  for (int c = 0; c < CT; ++c) acc[c] = (f32x4){0.f, 0.f, 0.f, 0.f};

#pragma unroll
  for (int t = 0; t < 4; ++t) {
    half8 a;
    if constexpr (HIN) {
      a = *(const half8*)((const _Float16*)Xp + (size_t)row * 128 + t * 32 + g * 8);
    } else {
      const float* xp = (const float*)Xp + (size_t)row * 128 + t * 32 + g * 8;
      float4 x0 = *(const float4*)xp;
      float4 x1 = *(const float4*)(xp + 4);
      a[0] = (_Float16)x0.x; a[1] = (_Float16)x0.y;
      a[2] = (_Float16)x0.z; a[3] = (_Float16)x0.w;
      a[4] = (_Float16)x1.x; a[5] = (_Float16)x1.y;
      a[6] = (_Float16)x1.z; a[7] = (_Float16)x1.w;
    }
#pragma unroll
    for (int c = 0; c < CT; ++c) {
      half8 b = *(const half8*)(Wp + (((size_t)t * M + c * 16 + r) * 4 + g) * 8);
      acc[c] = __builtin_amdgcn_mfma_f32_16x16x32_f16(a, b, acc[c], 0, 0, 0);
    }
  }

#pragma unroll
  for (int c = 0; c < CT; ++c) {
#pragma unroll
    for (int i = 0; i < 4; ++i) {
      int rr = row0 + 4 * g + i;
      if (rr < N) H[(size_t)rr * M + c * 16 + r] = (_Float16)acc[c][i];
    }
  }
}

// Load one masked 4-edge pack batch starting at e (clamped to e1-1, w=0 OOB)
__device__ __forceinline__ void pack_batch(const int2* __restrict__ pack,
                                           int e, int e1, int2* p) {
#pragma unroll
  for (int j = 0; j < 4; ++j) {
    int idx = e + j;
    bool ok = idx < e1;
    p[j] = pack[ok ? idx : (e1 - 1)];
    if (!ok) p[j].y = 0;  // w = 0.0f -> contributes exactly nothing
  }
}

// out[node] = di*( sum_e w_e*h[src_e] + di*h[node] ) + bias (+softmax).
// Static groups of F/8 lanes, one node per group. Rows processed as
// ceil(deg/4) masked 4-wide batches; pack stream pipelined one batch ahead.
template <int F, bool SM, bool OUTHALF>
__global__ __launch_bounds__(256) void aggregate(const __half* __restrict__ h,
                                                 const int* __restrict__ row_start,
                                                 const int2* __restrict__ pack,
                                                 const float* __restrict__ dinv,
                                                 const float* __restrict__ bias,
                                                 void* __restrict__ out, int n) {
  constexpr int LPG = F / 8;      // lanes per group: 16 (F=128) / 8 (F=64)
  constexpr int GPB = 256 / LPG;  // groups per block: 16 / 32
  const int node = blockIdx.x * GPB + (int)(threadIdx.x / LPG);
  const int lane = threadIdx.x % LPG;
  if (node >= n) return;

  const uint4* hv = (const uint4*)h;
  const float di = dinv[node];

  float acc[8];
  {
    uint4 su = hv[(size_t)node * LPG + lane];
    float sf[8];
    h8_to_f(su, sf);
#pragma unroll
    for (int i = 0; i < 8; ++i) acc[i] = di * sf[i];
  }

  const int e0 = row_start[node];
  const int e1 = row_start[node + 1];
  if (e0 < e1) {
    int2 p[4];
    pack_batch(pack, e0, e1, p);
    int e = e0;
    for (;;) {
      uint4 r[4];
#pragma unroll
      for (int j = 0; j < 4; ++j) r[j] = hv[(size_t)p[j].x * LPG + lane];
      const int en = e + 4;
      const bool more = en < e1;
      int2 pn[4];
      if (more) pack_batch(pack, en, e1, pn);
#pragma unroll
      for (int j = 0; j < 4; ++j) {
        float v[8];
        h8_to_f(r[j], v);
        fma8(acc, __int_as_float(p[j].y), v);
      }
      if (!more) break;
#pragma unroll
      for (int j = 0; j < 4; ++j) p[j] = pn[j];
      e = en;
    }
  }

  {
    const float4* bv = (const float4*)bias;
    float4 b0 = bv[lane * 2], b1 = bv[lane * 2 + 1];
    acc[0] = fmaf(di, acc[0], b0.x);
    acc[1] = fmaf(di, acc[1], b0.y);
    acc[2] = fmaf(di, acc[2], b0.z);
    acc[3] = fmaf(di, acc[3], b0.w);
    acc[4] = fmaf(di, acc[4], b1.x);
    acc[5] = fmaf(di, acc[5], b1.y);
    acc[6] = fmaf(di, acc[6], b1.z);
    acc[7] = fmaf(di, acc[7], b1.w);
  }

  if constexpr (SM) {
    float m = acc[0];
#pragma unroll
    for (int i = 1; i < 8; ++i) m = fmaxf(m, acc[i]);
#pragma unroll
    for (int off = LPG / 2; off >= 1; off >>= 1) m = fmaxf(m, __shfl_xor(m, off));
    float ex[8], ssum = 0.f;
#pragma unroll
    for (int i = 0; i < 8; ++i) {
      ex[i] = __expf(acc[i] - m);
      ssum += ex[i];
    }
#pragma unroll
    for (int off = LPG / 2; off >= 1; off >>= 1) ssum += __shfl_xor(ssum, off);
    float r = 1.0f / ssum;
#pragma unroll
    for (int i = 0; i < 8; ++i) acc[i] = ex[i] * r;
  }

  if constexpr (OUTHALF) {
    union { __half2 h2[4]; uint4 u; } cv;
#pragma unroll
    for (int i = 0; i < 4; ++i)
      cv.h2[i] = __floats2half2_rn(acc[2 * i], acc[2 * i + 1]);
    ((uint4*)out)[(size_t)node * LPG + lane] = cv.u;
  } else {
    float4* ov = (float4*)out;
    ov[(size_t)node * (F / 4) + lane * 2] =
        make_float4(acc[0], acc[1], acc[2], acc[3]);
    ov[(size_t)node * (F / 4) + lane * 2 + 1] =
        make_float4(acc[4], acc[5], acc[6], acc[7]);
  }
}

extern "C" void kernel_launch(void* const* d_in, const int* in_sizes, int n_in,
                              void* d_out, int out_size, void* d_ws, size_t ws_size,
                              hipStream_t stream) {
  const float* x  = (const float*)d_in[0];
  const float* W1 = (const float*)d_in[1];
  const float* b1 = (const float*)d_in[2];
  const float* W2 = (const float*)d_in[3];
  const float* b2 = (const float*)d_in[4];
  const int*   ei = (const int*)d_in[5];

  const int N = in_sizes[0] / 128;
  const int E = in_sizes[5] / 2;
  const int NB = (N + 255) >> BSHIFT;          // 391 for N=100K (<= NBPAD)
  const int SLICE = (E + NWG - 1) / NWG;
  const int* srcp = ei;
  const int* dstp = ei + E;

  auto align256 = [](size_t v) { return (v + 255) & ~(size_t)255; };
  char* ws = (char*)d_ws;
  size_t o_dinv   = 0;
  size_t o_rs     = align256(o_dinv + (size_t)N * 4);
  size_t o_cnts   = align256(o_rs + (size_t)(N + 1) * 4);
  size_t o_cur    = align256(o_cnts + (size_t)NWG * NBPAD * 4);
  size_t o_bstart = align256(o_cur + (size_t)NWG * NBPAD * 4);
  size_t o_wp1    = align256(o_bstart + (size_t)(NBPAD + 1) * 4);
  size_t o_wp2    = align256(o_wp1 + (size_t)128 * 128 * 2);
  size_t o_stg    = align256(o_wp2 + (size_t)128 * 64 * 2);
  size_t o_pack   = align256(o_stg + (size_t)E * 4);
  size_t o_h1     = align256(o_pack + (size_t)E * 8);
  size_t o_s      = align256(o_h1 + (size_t)N * 128 * 2);

  float*    dinv     = (float*)(ws + o_dinv);
  int*      rowstart = (int*)(ws + o_rs);
  int*      counts   = (int*)(ws + o_cnts);
  int*      cur      = (int*)(ws + o_cur);
  int*      bstart   = (int*)(ws + o_bstart);
  _Float16* wp1      = (_Float16*)(ws + o_wp1);
  _Float16* wp2      = (_Float16*)(ws + o_wp2);
  unsigned* staging  = (unsigned*)(ws + o_stg);
  int2*     pack     = (int2*)(ws + o_pack);
  _Float16* h1       = (_Float16*)(ws + o_h1);  // [N,128] fp16; reused as h2 [N,64]
  _Float16* sbuf     = (_Float16*)(ws + o_s);   // [N,128] fp16 softmax output

  // CSR build — no global atomics anywhere
  wg_count<<<NWG, 256, 0, stream>>>(dstp, counts, E, NB, SLICE);
  scan_buckets<<<1, 1024, 0, stream>>>(counts, bstart, rowstart, NB, N, E);
  cell_scan<<<NB, 256, 0, stream>>>(counts, bstart, cur, NB);
  wg_scatter<<<NWG, 256, 0, stream>>>(srcp, dstp, cur, staging, E, NB, SLICE);
  bucket_hist<<<NB, 256, 0, stream>>>(staging, bstart, rowstart, dinv, N);
  bucket_pack<<<NB, 256, 0, stream>>>(staging, bstart, rowstart, dinv, pack, N);

  // Weight packing (tiny)
  pack_w<128><<<(128 * 128 + 255) / 256, 256, 0, stream>>>(W1, wp1);
  pack_w<64><<<(128 * 64 + 255) / 256, 256, 0, stream>>>(W2, wp2);

  // Layer 1
  gemm_mfma<128, false><<<(N + 63) / 64, 256, 0, stream>>>(x, wp1, h1, N);
  aggregate<128, true, true><<<(N + 15) / 16, 256, 0, stream>>>(
      (const __half*)h1, rowstart, pack, dinv, b1, sbuf, N);
  // Layer 2
  gemm_mfma<64, true><<<(N + 63) / 64, 256, 0, stream>>>(sbuf, wp2, h1, N);
  aggregate<64, false, false><<<(N + 31) / 32, 256, 0, stream>>>(
      (const __half*)h1, rowstart, pack, dinv, b2, d_out, N);
}

// Round 15
// 192.442 us; speedup vs baseline: 1.1926x; 1.0532x over previous
//
#include <hip/hip_runtime.h>
#include <hip/hip_fp16.h>
#include <cstdint>
#include <cstddef>

// ---------------------------------------------------------------------------
// 2-layer GCN: h1 = x@W1; s = softmax(A_norm@h1 + b1); out = A_norm@(s@W2) + b2
// CSR build: wg-private two-level counting sort (zero global atomics);
// bucket totals come from cell_scan; tiny 1-block scan over 391 totals.
// GEMMs: fp16 MFMA (v_mfma_f32_16x16x32_f16), zero LDS, pre-packed W.
// Aggregation: 16/8-lane groups; masked 4-wide batches; TWO-DEEP pipeline
// (pack 2 batches ahead, row gathers 1 batch ahead) so batch k+1's gathers
// are in flight while batch k's FMAs run.
// ---------------------------------------------------------------------------

#define BSHIFT 8              // 256 nodes per bucket
#define NBPAD 512             // padded bucket count (NB=391 for N=100K)
#define NWG 256               // edge slices / scatter workgroups
#define CAP 6144              // LDS reorder buffer (mean bucket ~4096 edges)

typedef _Float16 half8 __attribute__((ext_vector_type(8)));
typedef float f32x4 __attribute__((ext_vector_type(4)));

__device__ __forceinline__ void h8_to_f(const uint4& u, float* f) {
  const __half2* hp = (const __half2*)&u;
#pragma unroll
  for (int i = 0; i < 4; ++i) {
    float2 t = __half22float2(hp[i]);
    f[2 * i] = t.x;
    f[2 * i + 1] = t.y;
  }
}

__device__ __forceinline__ void fma8(float* acc, float w, const float* v) {
#pragma unroll
  for (int i = 0; i < 8; ++i) acc[i] = fmaf(w, v[i], acc[i]);
}

// inclusive scan of v across a 256-thread block; wsums is __shared__ int[4]
__device__ __forceinline__ int block_scan256(int v, int* wsums) {
  const int lane = threadIdx.x & 63;
  const int wid = threadIdx.x >> 6;
  int x = v;
#pragma unroll
  for (int d = 1; d < 64; d <<= 1) {
    int y = __shfl_up(x, d);
    if (lane >= d) x += y;
  }
  if (lane == 63) wsums[wid] = x;
  __syncthreads();
  int off = 0;
#pragma unroll
  for (int j = 0; j < 4; ++j)
    if (j < wid) off += wsums[j];
  return off + x;
}

// Pass 1: per-wg LDS histogram of its edge slice -> counts[wg*NBPAD + b]
__global__ __launch_bounds__(256) void wg_count(const int* __restrict__ dst,
                                                int* __restrict__ counts,
                                                int E, int nb, int slice) {
  __shared__ int lh[NBPAD];
  const int w = blockIdx.x;
  for (int i = threadIdx.x; i < nb; i += 256) lh[i] = 0;
  __syncthreads();
  const int e0 = w * slice;
  const int e1 = min(e0 + slice, E);
  for (int e = e0 + threadIdx.x; e < e1; e += 256)
    atomicAdd(&lh[dst[e] >> BSHIFT], 1);
  __syncthreads();
  for (int i = threadIdx.x; i < nb; i += 256) counts[(size_t)w * NBPAD + i] = lh[i];
}

// Pass 2: one block per bucket — exclusive scan across wgs -> cur[wg][b]
// (LOCAL offsets, bstart added later) + per-bucket total -> btotal[b]
__global__ __launch_bounds__(256) void cell_scan(const int* __restrict__ counts,
                                                 int* __restrict__ cur,
                                                 int* __restrict__ btotal, int nb) {
  __shared__ int wsums[4];
  const int b = blockIdx.x;
  const int tid = threadIdx.x;
  int v = counts[(size_t)tid * NBPAD + b];
  int incl = block_scan256(v, wsums);
  cur[(size_t)tid * NBPAD + b] = incl - v;
  if (tid == 255) btotal[b] = incl;
}

// Pass 3: single tiny block — exclusive scan over nb bucket totals -> bstart
__global__ __launch_bounds__(1024) void bscan(const int* __restrict__ btotal,
                                              int* __restrict__ bstart,
                                              int* __restrict__ row_start,
                                              int nb, int n, int E) {
  __shared__ int wsum[16];
  const int tid = threadIdx.x;
  const int lane = tid & 63;
  const int wid = tid >> 6;
  int v = (tid < nb) ? btotal[tid] : 0;
  int x = v;
#pragma unroll
  for (int d = 1; d < 64; d <<= 1) {
    int y = __shfl_up(x, d);
    if (lane >= d) x += y;
  }
  if (lane == 63) wsum[wid] = x;
  __syncthreads();
  if (wid == 0) {
    int w = (lane < 16) ? wsum[lane] : 0;
#pragma unroll
    for (int d = 1; d < 16; d <<= 1) {
      int y = __shfl_up(w, d);
      if (lane >= d) w += y;
    }
    if (lane < 16) wsum[lane] = w;
  }
  __syncthreads();
  int boff = (wid > 0) ? wsum[wid - 1] : 0;
  int incl = boff + x;
  if (tid < nb) {
    bstart[tid] = incl - v;
    if (tid == nb - 1) bstart[nb] = incl;
  }
  if (tid == 0) row_start[n] = E;
}

// Pass 4: scatter with LDS cursors (cur local + bstart) — each (wg,bucket)
// range written by one wg
__global__ __launch_bounds__(256) void wg_scatter(const int* __restrict__ src,
                                                  const int* __restrict__ dst,
                                                  const int* __restrict__ cur,
                                                  const int* __restrict__ bstart,
                                                  unsigned* __restrict__ staging,
                                                  int E, int nb, int slice) {
  __shared__ int lc[NBPAD];
  const int w = blockIdx.x;
  for (int i = threadIdx.x; i < nb; i += 256)
    lc[i] = cur[(size_t)w * NBPAD + i] + bstart[i];
  __syncthreads();
  const int e0 = w * slice;
  const int e1 = min(e0 + slice, E);
  for (int e = e0 + threadIdx.x; e < e1; e += 256) {
    int d = dst[e];
    int p = atomicAdd(&lc[d >> BSHIFT], 1);
    staging[p] = ((unsigned)(d & 255) << 24) | (unsigned)src[e];
  }
}

// Pass 5a: per-bucket histogram -> row_start, dinv
__global__ __launch_bounds__(256) void bucket_hist(const unsigned* __restrict__ staging,
                                                   const int* __restrict__ bstart,
                                                   int* __restrict__ row_start,
                                                   float* __restrict__ dinv, int n) {
  __shared__ int lcnt[256];
  __shared__ int wsums[4];
  const int b = blockIdx.x;
  const int tid = threadIdx.x;
  const int n0 = b << BSHIFT;
  const int s0 = bstart[b];
  const int cnt = bstart[b + 1] - s0;

  lcnt[tid] = 0;
  __syncthreads();
  for (int i = tid; i < cnt; i += 256)
    atomicAdd(&lcnt[staging[s0 + i] >> 24], 1);
  __syncthreads();

  const int v = lcnt[tid];
  const int incl = block_scan256(v, wsums);
  const int node = n0 + tid;
  if (node < n) {
    row_start[node] = s0 + incl - v;
    dinv[node] = rsqrtf((float)v + 1.0f);
  }
}

// Pass 5b: per-bucket reorder -> pack[(src, dinv[src])] directly (no csr_src)
__global__ __launch_bounds__(256) void bucket_pack(const unsigned* __restrict__ staging,
                                                   const int* __restrict__ bstart,
                                                   const int* __restrict__ row_start,
                                                   const float* __restrict__ dinv,
                                                   int2* __restrict__ pack, int n) {
  __shared__ int lcur[256];
  __shared__ int lbuf[CAP];
  const int b = blockIdx.x;
  const int tid = threadIdx.x;
  const int n0 = b << BSHIFT;
  const int s0 = bstart[b];
  const int cnt = bstart[b + 1] - s0;

  const int node = n0 + tid;
  lcur[tid] = (node < n) ? (row_start[node] - s0) : 0;
  __syncthreads();

  for (int i = tid; i < cnt; i += 256) {
    unsigned p = staging[s0 + i];
    int pos = atomicAdd(&lcur[p >> 24], 1);
    int s = (int)(p & 0xFFFFFFu);
    if (pos < CAP) lbuf[pos] = s;
    else pack[s0 + pos] = make_int2(s, __float_as_int(dinv[s]));  // overflow
  }
  __syncthreads();
  const int lim = cnt < CAP ? cnt : CAP;
  for (int i = tid; i < lim; i += 256) {
    int s = lbuf[i];
    pack[s0 + i] = make_int2(s, __float_as_int(dinv[s]));
  }
}

// Pack W[128][M] fp32 -> Wp fp16 fragment order:
// Wp[((t*M + c)*4 + g)*8 + j] = W[t*32 + g*8 + j][c]
template <int M>
__global__ __launch_bounds__(256) void pack_w(const float* __restrict__ W,
                                              _Float16* __restrict__ Wp) {
  int e = blockIdx.x * 256 + threadIdx.x;
  if (e < 128 * M) {
    int k = e / M, c = e % M;
    int t = k >> 5, g = (k >> 3) & 3, j = k & 7;
    Wp[(((size_t)t * M + c) * 4 + g) * 8 + j] = (_Float16)W[e];
  }
}

// H[N,M] = X[N,128] @ W[128,M] via v_mfma_f32_16x16x32_f16. Zero LDS.
template <int M, bool HIN>
__global__ __launch_bounds__(256) void gemm_mfma(const void* __restrict__ Xp,
                                                 const _Float16* __restrict__ Wp,
                                                 _Float16* __restrict__ H, int N) {
  constexpr int CT = M / 16;
  const int wave = threadIdx.x >> 6;
  const int lane = threadIdx.x & 63;
  const int row0 = (blockIdx.x * 4 + wave) * 16;
  if (row0 >= N) return;
  const int r = lane & 15;
  const int g = lane >> 4;
  int row = row0 + r;
  if (row >= N) row = N - 1;

  f32x4 acc[CT];
#pragma unroll
  for (int c = 0; c < CT; ++c) acc[c] = (f32x4){0.f, 0.f, 0.f, 0.f};

#pragma unroll
  for (int t = 0; t < 4; ++t) {
    half8 a;
    if constexpr (HIN) {
      a = *(const half8*)((const _Float16*)Xp + (size_t)row * 128 + t * 32 + g * 8);
    } else {
      const float* xp = (const float*)Xp + (size_t)row * 128 + t * 32 + g * 8;
      float4 x0 = *(const float4*)xp;
      float4 x1 = *(const float4*)(xp + 4);
      a[0] = (_Float16)x0.x; a[1] = (_Float16)x0.y;
      a[2] = (_Float16)x0.z; a[3] = (_Float16)x0.w;
      a[4] = (_Float16)x1.x; a[5] = (_Float16)x1.y;
      a[6] = (_Float16)x1.z; a[7] = (_Float16)x1.w;
    }
#pragma unroll
    for (int c = 0; c < CT; ++c) {
      half8 b = *(const half8*)(Wp + (((size_t)t * M + c * 16 + r) * 4 + g) * 8);
      acc[c] = __builtin_amdgcn_mfma_f32_16x16x32_f16(a, b, acc[c], 0, 0, 0);
    }
  }

#pragma unroll
  for (int c = 0; c < CT; ++c) {
#pragma unroll
    for (int i = 0; i < 4; ++i) {
      int rr = row0 + 4 * g + i;
      if (rr < N) H[(size_t)rr * M + c * 16 + r] = (_Float16)acc[c][i];
    }
  }
}

// Load one masked 4-edge pack batch starting at e (clamped to e1-1, w=0 OOB)
__device__ __forceinline__ void pack_batch(const int2* __restrict__ pack,
                                           int e, int e1, int2* p) {
#pragma unroll
  for (int j = 0; j < 4; ++j) {
    int idx = e + j;
    bool ok = idx < e1;
    p[j] = pack[ok ? idx : (e1 - 1)];
    if (!ok) p[j].y = 0;  // w = 0.0f -> contributes exactly nothing
  }
}

// out[node] = di*( sum_e w_e*h[src_e] + di*h[node] ) + bias (+softmax).
// Static groups of F/8 lanes, one node per group. ceil(deg/4) masked 4-wide
// batches; TWO-DEEP pipeline: pack 2 ahead, gathers 1 ahead — batch k+1's
// row gathers are in flight while batch k's FMAs execute.
template <int F, bool SM, bool OUTHALF>
__global__ __launch_bounds__(256) void aggregate(const __half* __restrict__ h,
                                                 const int* __restrict__ row_start,
                                                 const int2* __restrict__ pack,
                                                 const float* __restrict__ dinv,
                                                 const float* __restrict__ bias,
                                                 void* __restrict__ out, int n) {
  constexpr int LPG = F / 8;      // lanes per group: 16 (F=128) / 8 (F=64)
  constexpr int GPB = 256 / LPG;  // groups per block: 16 / 32
  const int node = blockIdx.x * GPB + (int)(threadIdx.x / LPG);
  const int lane = threadIdx.x % LPG;
  if (node >= n) return;

  const uint4* hv = (const uint4*)h;
  const float di = dinv[node];

  float acc[8];
  {
    uint4 su = hv[(size_t)node * LPG + lane];
    float sf[8];
    h8_to_f(su, sf);
#pragma unroll
    for (int i = 0; i < 8; ++i) acc[i] = di * sf[i];
  }

  const int e0 = row_start[node];
  const int e1 = row_start[node + 1];
  const int nbat = (e1 - e0 + 3) >> 2;

  if (nbat > 0) {
    int2 p0[4], p1[4];
    uint4 r0[4];
    pack_batch(pack, e0, e1, p0);
#pragma unroll
    for (int j = 0; j < 4; ++j) r0[j] = hv[(size_t)p0[j].x * LPG + lane];
    if (nbat > 1) pack_batch(pack, e0 + 4, e1, p1);

    for (int k = 0; k < nbat; ++k) {
      uint4 r1[4];
      if (k + 1 < nbat) {
#pragma unroll
        for (int j = 0; j < 4; ++j) r1[j] = hv[(size_t)p1[j].x * LPG + lane];
      }
      int2 p2[4];
      if (k + 2 < nbat) pack_batch(pack, e0 + 4 * (k + 2), e1, p2);
#pragma unroll
      for (int j = 0; j < 4; ++j) {
        float v[8];
        h8_to_f(r0[j], v);
        fma8(acc, __int_as_float(p0[j].y), v);
      }
#pragma unroll
      for (int j = 0; j < 4; ++j) {
        p0[j] = p1[j];
        p1[j] = p2[j];
        r0[j] = r1[j];
      }
    }
  }

  {
    const float4* bv = (const float4*)bias;
    float4 b0 = bv[lane * 2], b1 = bv[lane * 2 + 1];
    acc[0] = fmaf(di, acc[0], b0.x);
    acc[1] = fmaf(di, acc[1], b0.y);
    acc[2] = fmaf(di, acc[2], b0.z);
    acc[3] = fmaf(di, acc[3], b0.w);
    acc[4] = fmaf(di, acc[4], b1.x);
    acc[5] = fmaf(di, acc[5], b1.y);
    acc[6] = fmaf(di, acc[6], b1.z);
    acc[7] = fmaf(di, acc[7], b1.w);
  }

  if constexpr (SM) {
    float m = acc[0];
#pragma unroll
    for (int i = 1; i < 8; ++i) m = fmaxf(m, acc[i]);
#pragma unroll
    for (int off = LPG / 2; off >= 1; off >>= 1) m = fmaxf(m, __shfl_xor(m, off));
    float ex[8], ssum = 0.f;
#pragma unroll
    for (int i = 0; i < 8; ++i) {
      ex[i] = __expf(acc[i] - m);
      ssum += ex[i];
    }
#pragma unroll
    for (int off = LPG / 2; off >= 1; off >>= 1) ssum += __shfl_xor(ssum, off);
    float r = 1.0f / ssum;
#pragma unroll
    for (int i = 0; i < 8; ++i) acc[i] = ex[i] * r;
  }

  if constexpr (OUTHALF) {
    union { __half2 h2[4]; uint4 u; } cv;
#pragma unroll
    for (int i = 0; i < 4; ++i)
      cv.h2[i] = __floats2half2_rn(acc[2 * i], acc[2 * i + 1]);
    ((uint4*)out)[(size_t)node * LPG + lane] = cv.u;
  } else {
    float4* ov = (float4*)out;
    ov[(size_t)node * (F / 4) + lane * 2] =
        make_float4(acc[0], acc[1], acc[2], acc[3]);
    ov[(size_t)node * (F / 4) + lane * 2 + 1] =
        make_float4(acc[4], acc[5], acc[6], acc[7]);
  }
}

extern "C" void kernel_launch(void* const* d_in, const int* in_sizes, int n_in,
                              void* d_out, int out_size, void* d_ws, size_t ws_size,
                              hipStream_t stream) {
  const float* x  = (const float*)d_in[0];
  const float* W1 = (const float*)d_in[1];
  const float* b1 = (const float*)d_in[2];
  const float* W2 = (const float*)d_in[3];
  const float* b2 = (const float*)d_in[4];
  const int*   ei = (const int*)d_in[5];

  const int N = in_sizes[0] / 128;
  const int E = in_sizes[5] / 2;
  const int NB = (N + 255) >> BSHIFT;          // 391 for N=100K (<= NBPAD)
  const int SLICE = (E + NWG - 1) / NWG;
  const int* srcp = ei;
  const int* dstp = ei + E;

  auto align256 = [](size_t v) { return (v + 255) & ~(size_t)255; };
  char* ws = (char*)d_ws;
  size_t o_dinv   = 0;
  size_t o_rs     = align256(o_dinv + (size_t)N * 4);
  size_t o_cnts   = align256(o_rs + (size_t)(N + 1) * 4);
  size_t o_cur    = align256(o_cnts + (size_t)NWG * NBPAD * 4);
  size_t o_btot   = align256(o_cur + (size_t)NWG * NBPAD * 4);
  size_t o_bstart = align256(o_btot + (size_t)NBPAD * 4);
  size_t o_wp1    = align256(o_bstart + (size_t)(NBPAD + 1) * 4);
  size_t o_wp2    = align256(o_wp1 + (size_t)128 * 128 * 2);
  size_t o_stg    = align256(o_wp2 + (size_t)128 * 64 * 2);
  size_t o_pack   = align256(o_stg + (size_t)E * 4);
  size_t o_h1     = align256(o_pack + (size_t)E * 8);
  size_t o_s      = align256(o_h1 + (size_t)N * 128 * 2);

  float*    dinv     = (float*)(ws + o_dinv);
  int*      rowstart = (int*)(ws + o_rs);
  int*      counts   = (int*)(ws + o_cnts);
  int*      cur      = (int*)(ws + o_cur);
  int*      btotal   = (int*)(ws + o_btot);
  int*      bstart   = (int*)(ws + o_bstart);
  _Float16* wp1      = (_Float16*)(ws + o_wp1);
  _Float16* wp2      = (_Float16*)(ws + o_wp2);
  unsigned* staging  = (unsigned*)(ws + o_stg);
  int2*     pack     = (int2*)(ws + o_pack);
  _Float16* h1       = (_Float16*)(ws + o_h1);  // [N,128] fp16; reused as h2 [N,64]
  _Float16* sbuf     = (_Float16*)(ws + o_s);   // [N,128] fp16 softmax output

  // CSR build — no global atomics anywhere
  wg_count<<<NWG, 256, 0, stream>>>(dstp, counts, E, NB, SLICE);
  cell_scan<<<NB, 256, 0, stream>>>(counts, cur, btotal, NB);
  bscan<<<1, 1024, 0, stream>>>(btotal, bstart, rowstart, NB, N, E);
  wg_scatter<<<NWG, 256, 0, stream>>>(srcp, dstp, cur, bstart, staging, E, NB, SLICE);
  bucket_hist<<<NB, 256, 0, stream>>>(staging, bstart, rowstart, dinv, N);
  bucket_pack<<<NB, 256, 0, stream>>>(staging, bstart, rowstart, dinv, pack, N);

  // Weight packing (tiny)
  pack_w<128><<<(128 * 128 + 255) / 256, 256, 0, stream>>>(W1, wp1);
  pack_w<64><<<(128 * 64 + 255) / 256, 256, 0, stream>>>(W2, wp2);

  // Layer 1
  gemm_mfma<128, false><<<(N + 63) / 64, 256, 0, stream>>>(x, wp1, h1, N);
  aggregate<128, true, true><<<(N + 15) / 16, 256, 0, stream>>>(
      (const __half*)h1, rowstart, pack, dinv, b1, sbuf, N);
  // Layer 2
  gemm_mfma<64, true><<<(N + 63) / 64, 256, 0, stream>>>(sbuf, wp2, h1, N);
  aggregate<64, false, false><<<(N + 31) / 32, 256, 0, stream>>>(
      (const __half*)h1, rowstart, pack, dinv, b2, d_out, N);
}